// Round 1
// baseline (131.716 us; speedup 1.0000x reference)
//
#include <hip/hip_runtime.h>

// Geometry constants (from the reference)
constexpr int   CC      = 128;               // channels per slice (LAST_DIM)
constexpr int   WSTRIDE = 9 * 128;           // floats per W step  (1152)
constexpr int   HSTRIDE = 96 * WSTRIDE;      // floats per H step
constexpr long  BSTRIDE = 64L * HSTRIDE;     // floats per batch image

__global__ __launch_bounds__(64)
void rroi_pool_kernel(const float* __restrict__ feat,
                      const float* __restrict__ rois,
                      float* __restrict__ out, int N) {
  const int n = blockIdx.x;
  if (n >= N) return;
  const int lane = threadIdx.x;              // lane owns channels 2*lane, 2*lane+1

  const float r0  = rois[n * 5 + 0];
  const float rx1 = rois[n * 5 + 1];
  const float ry1 = rois[n * 5 + 2];
  const float rx2 = rois[n * 5 + 3];
  const float ry2 = rois[n * 5 + 4];
  const int b = (int)r0;

  // normalized box [y1,x1,y2,x2]
  const float x1 = rx1 / 1536.0f;
  const float y1 = ry1 / 1024.0f;
  const float x2 = rx2 / 1536.0f;
  const float y2 = ry2 / 1024.0f;

  const float bin_w = (x2 - x1) / 3.0f;
  const float bin_h = y2 - y1 / 3.0f;        // faithful to reference (precedence bug kept)

  float acc0 = 0.0f, acc1 = 0.0f;
  const float* fb_batch = feat + (size_t)b * BSTRIDE + 2 * lane;

  for (int ih = 0; ih < 3; ++ih) {
    for (int iw = 0; iw < 3; ++iw) {
      const int idx = ih * 3 + iw;
      const float by1 = y1 + (float)ih * bin_h;
      const float bx1 = x1 + (float)iw * bin_w;
      const float by2 = y1 + (float)(ih + 1) * bin_h;
      const float bx2 = x1 + (float)(iw + 1) * bin_h;  // faithful: bin_h here (reference bug)

      const float ystep = ((by2 - by1) * 63.0f) / 5.0f;
      const float xstep = ((bx2 - bx1) * 95.0f) / 5.0f;
      const float ybase = by1 * 63.0f;
      const float xbase = bx1 * 95.0f;

      // precompute x-sample info (fully unrolled -> registers)
      int   xo0[6], xo1[6];
      float lx[6];
      bool  vx[6];
#pragma unroll
      for (int sx = 0; sx < 6; ++sx) {
        const float xs = xbase + (float)sx * xstep;
        vx[sx] = (xs >= 0.0f) && (xs <= 95.0f);
        const float xf = floorf(xs);
        lx[sx] = xs - xf;
        int xi = (int)xf;
        xi = xi < 0 ? 0 : (xi > 95 ? 95 : xi);
        const int xj = (xi + 1 > 95) ? 95 : xi + 1;
        xo0[sx] = xi * WSTRIDE;
        xo1[sx] = xj * WSTRIDE;
      }

      const float* fb = fb_batch + idx * CC;
#pragma unroll
      for (int sy = 0; sy < 6; ++sy) {
        const float ys = ybase + (float)sy * ystep;
        if (!((ys >= 0.0f) && (ys <= 63.0f))) continue;   // wave-uniform skip (mask==0)
        const float yf = floorf(ys);
        const float ly = ys - yf;
        int yi = (int)yf;
        yi = yi < 0 ? 0 : (yi > 63 ? 63 : yi);
        const int yj = (yi + 1 > 63) ? 63 : yi + 1;
        const float* row0 = fb + (size_t)yi * HSTRIDE;
        const float* row1 = fb + (size_t)yj * HSTRIDE;
#pragma unroll
        for (int sx = 0; sx < 6; ++sx) {
          if (!vx[sx]) continue;                          // wave-uniform skip
          const float l = lx[sx];
          const float2 v00 = *(const float2*)(row0 + xo0[sx]);
          const float2 v01 = *(const float2*)(row0 + xo1[sx]);
          const float2 v10 = *(const float2*)(row1 + xo0[sx]);
          const float2 v11 = *(const float2*)(row1 + xo1[sx]);
          const float t0 = v00.x * (1.0f - l) + v01.x * l;
          const float t1 = v00.y * (1.0f - l) + v01.y * l;
          const float u0 = v10.x * (1.0f - l) + v11.x * l;
          const float u1 = v10.y * (1.0f - l) + v11.y * l;
          acc0 += t0 * (1.0f - ly) + u0 * ly;
          acc1 += t1 * (1.0f - ly) + u1 * ly;
        }
      }
    }
  }

  const float scale = 1.0f / 324.0f;   // (/9 for the 9 sub-boxes) * (/36 spatial mean)
  out[(size_t)n * CC + 2 * lane]     = acc0 * scale;
  out[(size_t)n * CC + 2 * lane + 1] = acc1 * scale;
}

extern "C" void kernel_launch(void* const* d_in, const int* in_sizes, int n_in,
                              void* d_out, int out_size, void* d_ws, size_t ws_size,
                              hipStream_t stream) {
  const float* feat = (const float*)d_in[0];   // (4,64,96,1152) f32
  const float* rois = (const float*)d_in[1];   // (2048,5) f32
  float* out = (float*)d_out;                  // (1,2048,128) f32
  const int N = in_sizes[1] / 5;
  rroi_pool_kernel<<<N, 64, 0, stream>>>(feat, rois, out, N);
}

// Round 2
// 97.989 us; speedup vs baseline: 1.3442x; 1.3442x over previous
//
#include <hip/hip_runtime.h>

// Geometry constants (from the reference)
constexpr int   CC      = 128;               // channels per slice (LAST_DIM)
constexpr int   WSTRIDE = 9 * 128;           // floats per W step  (1152)
constexpr int   HSTRIDE = 96 * WSTRIDE;      // floats per H step
constexpr long  BSTRIDE = 64L * HSTRIDE;     // floats per batch image

// One block per ROI; 9 waves per block, wave w handles sub-box idx w.
// Each lane owns channels 2*lane, 2*lane+1 (float2 loads, fully coalesced).
__global__ __launch_bounds__(576)
void rroi_pool_kernel(const float* __restrict__ feat,
                      const float* __restrict__ rois,
                      float* __restrict__ out, int N) {
  const int n = blockIdx.x;
  const int wid  = threadIdx.x >> 6;         // 0..8 : sub-box index
  const int lane = threadIdx.x & 63;

  __shared__ float partial[9][CC];

  const float r0  = rois[n * 5 + 0];
  const float rx1 = rois[n * 5 + 1];
  const float ry1 = rois[n * 5 + 2];
  const float rx2 = rois[n * 5 + 3];
  const float ry2 = rois[n * 5 + 4];
  const int b = (int)r0;

  // normalized box [y1,x1,y2,x2]
  const float x1 = rx1 / 1536.0f;
  const float y1 = ry1 / 1024.0f;
  const float x2 = rx2 / 1536.0f;
  const float y2 = ry2 / 1024.0f;

  const float bin_w = (x2 - x1) / 3.0f;
  const float bin_h = y2 - y1 / 3.0f;        // faithful to reference (precedence bug kept)

  const int ih = wid / 3;
  const int iw = wid - 3 * ih;

  const float by1 = y1 + (float)ih * bin_h;
  const float bx1 = x1 + (float)iw * bin_w;
  const float by2 = y1 + (float)(ih + 1) * bin_h;
  const float bx2 = x1 + (float)(iw + 1) * bin_h;  // faithful: bin_h here (reference bug)

  const float ystep = ((by2 - by1) * 63.0f) / 5.0f;
  const float xstep = ((bx2 - bx1) * 95.0f) / 5.0f;
  const float ybase = by1 * 63.0f;
  const float xbase = bx1 * 95.0f;

  // precompute x-sample info (fully unrolled -> registers)
  int   xo0[6], xo1[6];
  float lx[6];
  bool  vx[6];
#pragma unroll
  for (int sx = 0; sx < 6; ++sx) {
    const float xs = xbase + (float)sx * xstep;
    vx[sx] = (xs >= 0.0f) && (xs <= 95.0f);
    const float xf = floorf(xs);
    lx[sx] = xs - xf;
    int xi = (int)xf;
    xi = xi < 0 ? 0 : (xi > 95 ? 95 : xi);
    const int xj = (xi + 1 > 95) ? 95 : xi + 1;
    xo0[sx] = xi * WSTRIDE;
    xo1[sx] = xj * WSTRIDE;
  }

  float acc0 = 0.0f, acc1 = 0.0f;
  const float* fb = feat + (size_t)b * BSTRIDE + wid * CC + 2 * lane;

#pragma unroll
  for (int sy = 0; sy < 6; ++sy) {
    const float ys = ybase + (float)sy * ystep;
    if (!((ys >= 0.0f) && (ys <= 63.0f))) continue;   // wave-uniform skip (mask==0)
    const float yf = floorf(ys);
    const float ly = ys - yf;
    int yi = (int)yf;
    yi = yi < 0 ? 0 : (yi > 63 ? 63 : yi);
    const int yj = (yi + 1 > 63) ? 63 : yi + 1;
    const float* row0 = fb + (size_t)yi * HSTRIDE;
    const float* row1 = fb + (size_t)yj * HSTRIDE;
#pragma unroll
    for (int sx = 0; sx < 6; ++sx) {
      if (!vx[sx]) continue;                          // wave-uniform skip
      const float l = lx[sx];
      const float2 v00 = *(const float2*)(row0 + xo0[sx]);
      const float2 v01 = *(const float2*)(row0 + xo1[sx]);
      const float2 v10 = *(const float2*)(row1 + xo0[sx]);
      const float2 v11 = *(const float2*)(row1 + xo1[sx]);
      const float t0 = v00.x * (1.0f - l) + v01.x * l;
      const float t1 = v00.y * (1.0f - l) + v01.y * l;
      const float u0 = v10.x * (1.0f - l) + v11.x * l;
      const float u1 = v10.y * (1.0f - l) + v11.y * l;
      acc0 += t0 * (1.0f - ly) + u0 * ly;
      acc1 += t1 * (1.0f - ly) + u1 * ly;
    }
  }

  partial[wid][2 * lane]     = acc0;
  partial[wid][2 * lane + 1] = acc1;
  __syncthreads();

  if (threadIdx.x < CC) {
    const float scale = 1.0f / 324.0f;  // (/9 sub-boxes) * (/36 spatial mean)
    float s = 0.0f;
#pragma unroll
    for (int w = 0; w < 9; ++w) s += partial[w][threadIdx.x];
    out[(size_t)n * CC + threadIdx.x] = s * scale;
  }
}

extern "C" void kernel_launch(void* const* d_in, const int* in_sizes, int n_in,
                              void* d_out, int out_size, void* d_ws, size_t ws_size,
                              hipStream_t stream) {
  const float* feat = (const float*)d_in[0];   // (4,64,96,1152) f32
  const float* rois = (const float*)d_in[1];   // (2048,5) f32
  float* out = (float*)d_out;                  // (1,2048,128) f32
  const int N = in_sizes[1] / 5;
  rroi_pool_kernel<<<N, 576, 0, stream>>>(feat, rois, out, N);
}

// Round 3
// 95.911 us; speedup vs baseline: 1.3733x; 1.0217x over previous
//
#include <hip/hip_runtime.h>

// Geometry constants (from the reference)
constexpr int   CC      = 128;               // channels per slice (LAST_DIM)
constexpr int   WSTRIDE = 9 * 128;           // floats per W step  (1152)
constexpr int   HSTRIDE = 96 * WSTRIDE;      // floats per H step
constexpr long  BSTRIDE = 64L * HSTRIDE;     // floats per batch image

// ---- device helper: one (ROI, sub-box) partial into acc0/acc1 -------------
__device__ __forceinline__ void subbox_accum(const float* __restrict__ feat,
                                             const float* __restrict__ rois,
                                             int n, int wid, int lane,
                                             float& acc0, float& acc1) {
  const float r0  = rois[n * 5 + 0];
  const float rx1 = rois[n * 5 + 1];
  const float ry1 = rois[n * 5 + 2];
  const float rx2 = rois[n * 5 + 3];
  const float ry2 = rois[n * 5 + 4];
  const int b = (int)r0;

  const float x1 = rx1 / 1536.0f;
  const float y1 = ry1 / 1024.0f;
  const float x2 = rx2 / 1536.0f;
  const float y2 = ry2 / 1024.0f;

  const float bin_w = (x2 - x1) / 3.0f;
  const float bin_h = y2 - y1 / 3.0f;        // faithful to reference (precedence bug kept)

  const int ih = wid / 3;
  const int iw = wid - 3 * ih;

  const float by1 = y1 + (float)ih * bin_h;
  const float bx1 = x1 + (float)iw * bin_w;
  const float by2 = y1 + (float)(ih + 1) * bin_h;
  const float bx2 = x1 + (float)(iw + 1) * bin_h;  // faithful: bin_h here (reference bug)

  const float ystep = ((by2 - by1) * 63.0f) / 5.0f;
  const float xstep = ((bx2 - bx1) * 95.0f) / 5.0f;
  const float ybase = by1 * 63.0f;
  const float xbase = bx1 * 95.0f;

  int   xo0[6], xo1[6];
  float lx[6];
  bool  vx[6];
#pragma unroll
  for (int sx = 0; sx < 6; ++sx) {
    const float xs = xbase + (float)sx * xstep;
    vx[sx] = (xs >= 0.0f) && (xs <= 95.0f);
    const float xf = floorf(xs);
    lx[sx] = xs - xf;
    int xi = (int)xf;
    xi = xi < 0 ? 0 : (xi > 95 ? 95 : xi);
    const int xj = (xi + 1 > 95) ? 95 : xi + 1;
    xo0[sx] = xi * WSTRIDE;
    xo1[sx] = xj * WSTRIDE;
  }

  const float* fb = feat + (size_t)b * BSTRIDE + wid * CC + 2 * lane;

#pragma unroll
  for (int sy = 0; sy < 6; ++sy) {
    const float ys = ybase + (float)sy * ystep;
    if (!((ys >= 0.0f) && (ys <= 63.0f))) continue;   // wave-uniform skip (mask==0)
    const float yf = floorf(ys);
    const float ly = ys - yf;
    int yi = (int)yf;
    yi = yi < 0 ? 0 : (yi > 63 ? 63 : yi);
    const int yj = (yi + 1 > 63) ? 63 : yi + 1;
    const float* row0 = fb + (size_t)yi * HSTRIDE;
    const float* row1 = fb + (size_t)yj * HSTRIDE;
#pragma unroll
    for (int sx = 0; sx < 6; ++sx) {
      if (!vx[sx]) continue;                          // wave-uniform skip
      const float l = lx[sx];
      const float2 v00 = *(const float2*)(row0 + xo0[sx]);
      const float2 v01 = *(const float2*)(row0 + xo1[sx]);
      const float2 v10 = *(const float2*)(row1 + xo0[sx]);
      const float2 v11 = *(const float2*)(row1 + xo1[sx]);
      const float t0 = v00.x * (1.0f - l) + v01.x * l;
      const float t1 = v00.y * (1.0f - l) + v01.y * l;
      const float u0 = v10.x * (1.0f - l) + v11.x * l;
      const float u1 = v10.y * (1.0f - l) + v11.y * l;
      acc0 += t0 * (1.0f - ly) + u0 * ly;
      acc1 += t1 * (1.0f - ly) + u1 * ly;
    }
  }
}

// ---- phase 1: one wave per (ROI, sub-box); partials to workspace ----------
__global__ __launch_bounds__(64)
void rroi_partial_kernel(const float* __restrict__ feat,
                         const float* __restrict__ rois,
                         float* __restrict__ ws) {
  const int wid  = blockIdx.x;       // 0..8  sub-box
  const int n    = blockIdx.y;       // ROI
  const int lane = threadIdx.x;

  float acc0 = 0.0f, acc1 = 0.0f;
  subbox_accum(feat, rois, n, wid, lane, acc0, acc1);

  float* p = ws + ((size_t)n * 9 + wid) * CC;
  p[2 * lane]     = acc0;
  p[2 * lane + 1] = acc1;
}

// ---- phase 2: reduce 9 partials per ROI -----------------------------------
__global__ __launch_bounds__(128)
void rroi_reduce_kernel(const float* __restrict__ ws,
                        float* __restrict__ out) {
  const int n = blockIdx.x;
  const int c = threadIdx.x;
  const float* p = ws + (size_t)n * 9 * CC + c;
  float s = 0.0f;
#pragma unroll
  for (int w = 0; w < 9; ++w) s += p[w * CC];
  out[(size_t)n * CC + c] = s * (1.0f / 324.0f);  // (/9 sub-boxes)*(/36 mean)
}

// ---- fallback: round-2 single-kernel (if ws too small) --------------------
__global__ __launch_bounds__(576)
void rroi_pool_kernel(const float* __restrict__ feat,
                      const float* __restrict__ rois,
                      float* __restrict__ out, int N) {
  const int n = blockIdx.x;
  const int wid  = threadIdx.x >> 6;
  const int lane = threadIdx.x & 63;
  __shared__ float partial[9][CC];

  float acc0 = 0.0f, acc1 = 0.0f;
  subbox_accum(feat, rois, n, wid, lane, acc0, acc1);

  partial[wid][2 * lane]     = acc0;
  partial[wid][2 * lane + 1] = acc1;
  __syncthreads();

  if (threadIdx.x < CC) {
    float s = 0.0f;
#pragma unroll
    for (int w = 0; w < 9; ++w) s += partial[w][threadIdx.x];
    out[(size_t)n * CC + threadIdx.x] = s * (1.0f / 324.0f);
  }
}

extern "C" void kernel_launch(void* const* d_in, const int* in_sizes, int n_in,
                              void* d_out, int out_size, void* d_ws, size_t ws_size,
                              hipStream_t stream) {
  const float* feat = (const float*)d_in[0];   // (4,64,96,1152) f32
  const float* rois = (const float*)d_in[1];   // (2048,5) f32
  float* out = (float*)d_out;                  // (1,2048,128) f32
  const int N = in_sizes[1] / 5;

  const size_t need = (size_t)N * 9 * CC * sizeof(float);
  if (ws_size >= need) {
    float* ws = (float*)d_ws;
    dim3 grid1(9, N);
    rroi_partial_kernel<<<grid1, 64, 0, stream>>>(feat, rois, ws);
    rroi_reduce_kernel<<<N, 128, 0, stream>>>(ws, out);
  } else {
    rroi_pool_kernel<<<N, 576, 0, stream>>>(feat, rois, out, N);
  }
}